// Round 6
// baseline (275.916 us; speedup 1.0000x reference)
//
#include <hip/hip_runtime.h>
#include <cstdint>
#include <cstddef>

#define BATCH 4
#define NPTS 8192
#define CHUNK 128           // db points per block (NPTS / 64 chunks)
#define BLOCK 256           // threads per block
#define QPT 8               // queries per thread
#define QPB (BLOCK * QPT)   // 2048 queries per block
#define NKEYS (2 * BATCH * NPTS)  // 65536
// grid = (NPTS/QPB) x (NPTS/CHUNK) x (2*BATCH) = 4 x 64 x 8 = 2048 blocks
// = 8 blocks/CU, 32 waves/CU. launch_bounds(256,8) pins VGPR <= 64 (r5's
// compiled allocation was exactly 64, so no spill expected); LDS 2KB/block.

// ---------------------------------------------------------------------------
// Shared bit-exact helpers (used by nn staging, nn loop, and mid resolve —
// explicit fmaf chains so both kernels produce identical bits).
// ---------------------------------------------------------------------------
__device__ __forceinline__ float halfnorm(float px, float py, float pz) {
    return 0.5f * fmaf(pz, pz, fmaf(py, py, px * px));
}
__device__ __forceinline__ float score(float qx, float qy, float qz,
                                       float px, float py, float pz, float ph) {
    float t = fmaf(-qx, px, ph);
    t = fmaf(-qy, py, t);
    return fmaf(-qz, pz, t);
}
__device__ __forceinline__ unsigned int mono_f32(float f) {
    unsigned int u = __float_as_uint(f);
    return u ^ (unsigned int)(((int)u >> 31) | 0x80000000);
}

// ---------------------------------------------------------------------------
// Pass 1: brute-force NN.  s = 0.5*|p|^2 - q.p  (ordering == |q-p|^2).
// Group-of-8 min3 tree; only the winning GROUP BASE is tracked (strict <
// keeps earliest group). Cross-chunk combine: atomicMin on u64 key
//   (mono(s)<<32) | group_base  -> ties pick smallest base (first occurrence).
// Within-group index resolved later in mid_kernel (bit-identical recompute).
// Side duty (ct==0 blocks): zero counts/esum, out = 1.0.
// ---------------------------------------------------------------------------
__global__ void __launch_bounds__(BLOCK, 8) nn_kernel(
        const float* __restrict__ xyz1,
        const float* __restrict__ xyz2,
        unsigned long long* __restrict__ keys,
        unsigned int* __restrict__ counts,
        float* __restrict__ esum,
        float* __restrict__ out) {
    __shared__ float lx[CHUNK];
    __shared__ float ly[CHUNK];
    __shared__ float lz[CHUNK];
    __shared__ float lh[CHUNK];

    const int tid = threadIdx.x;
    const int qt  = blockIdx.x;      // 0..3   query tile (2048 queries)
    const int ct  = blockIdx.y;      // 0..63  db chunk (128 points)
    const int zb  = blockIdx.z;      // 0..7   dir*4 + b
    const int b   = zb & 3;
    const int dir = zb >> 2;
    const float* q_ptr = (dir == 0) ? xyz2 : xyz1;
    const float* d_ptr = (dir == 0) ? xyz1 : xyz2;
    const int chunk0 = ct * CHUNK;

    // ---- side duty (ct==0: 32 blocks x 256 threads = 8192 threads) ----
    if (ct == 0) {
        const int tz = (zb * 4 + qt) * BLOCK + tid;   // 0..8191
#pragma unroll
        for (int k = 0; k < 8; ++k) {
            counts[tz * 8 + k] = 0u;
            esum[tz * 8 + k] = 0.0f;
        }
        if (tz == 0) out[0] = 1.0f;
    }

    // ---- stage db chunk into LDS (SoA + half-norm) ----
    // CHUNK*3 = 384 floats = 96 float4; threads 0..31 load 3 float4 each
    if (tid < 32) {
        const float4* g4 = (const float4*)(d_ptr + (size_t)(b * NPTS + chunk0) * 3);
        float4 t0 = g4[3 * tid + 0];
        float4 t1 = g4[3 * tid + 1];
        float4 t2 = g4[3 * tid + 2];
        float px[4] = {t0.x, t0.w, t1.z, t2.y};
        float py[4] = {t0.y, t1.x, t1.w, t2.z};
        float pz[4] = {t0.z, t1.y, t2.x, t2.w};
#pragma unroll
        for (int i = 0; i < 4; ++i) {
            lx[4 * tid + i] = px[i];
            ly[4 * tid + i] = py[i];
            lz[4 * tid + i] = pz[i];
            lh[4 * tid + i] = halfnorm(px[i], py[i], pz[i]);
        }
    }

    // ---- this thread's QPT query points (stride BLOCK for coalescing) ----
    const int qbase = qt * QPB + tid;
    float qx[QPT], qy[QPT], qz[QPT];
#pragma unroll
    for (int u = 0; u < QPT; ++u) {
        const float* qp = q_ptr + (size_t)(b * NPTS + qbase + u * BLOCK) * 3;
        qx[u] = qp[0]; qy[u] = qp[1]; qz[u] = qp[2];
    }

    __syncthreads();

    float bd[QPT];
    int   bj[QPT];
#pragma unroll
    for (int u = 0; u < QPT; ++u) { bd[u] = 3.4e38f; bj[u] = 0; }

    for (int j = 0; j < CHUNK; j += 8) {
        float px[8], py[8], pz[8], ph[8];
        *(float4*)&px[0] = *(const float4*)(lx + j);
        *(float4*)&px[4] = *(const float4*)(lx + j + 4);
        *(float4*)&py[0] = *(const float4*)(ly + j);
        *(float4*)&py[4] = *(const float4*)(ly + j + 4);
        *(float4*)&pz[0] = *(const float4*)(lz + j);
        *(float4*)&pz[4] = *(const float4*)(lz + j + 4);
        *(float4*)&ph[0] = *(const float4*)(lh + j);
        *(float4*)&ph[4] = *(const float4*)(lh + j + 4);

#pragma unroll
        for (int u = 0; u < QPT; ++u) {
            float s[8];
#pragma unroll
            for (int k = 0; k < 8; ++k)
                s[k] = score(qx[u], qy[u], qz[u], px[k], py[k], pz[k], ph[k]);
            float m0 = fminf(fminf(s[0], s[1]), s[2]);   // v_min3
            float m1 = fminf(fminf(s[3], s[4]), s[5]);   // v_min3
            float m2 = fminf(fminf(s[6], s[7]), m0);     // v_min3
            float m  = fminf(m1, m2);
            if (m < bd[u]) { bd[u] = m; bj[u] = j; }     // strict <: earliest group
        }
    }

    const size_t base = ((size_t)zb) * NPTS;
#pragma unroll
    for (int u = 0; u < QPT; ++u) {
        unsigned long long key =
            ((unsigned long long)mono_f32(bd[u]) << 32) |
            (unsigned int)(chunk0 + bj[u]);
        atomicMin(&keys[base + qbase + u * BLOCK], key);
    }
}

// ---------------------------------------------------------------------------
// Pass 2 (mid): per query — resolve argmin within the winning group of 8 by
// bit-identical recompute from global memory, then accumulate histogram
// count and exp(-1000*d_exact) per chosen db point.
// ---------------------------------------------------------------------------
__global__ void __launch_bounds__(BLOCK) mid_kernel(
        const float* __restrict__ xyz1,
        const float* __restrict__ xyz2,
        const unsigned long long* __restrict__ keys,
        unsigned int* __restrict__ counts,
        float* __restrict__ esum) {
    const int gtid = blockIdx.x * BLOCK + threadIdx.x;  // 0..65535
    const int group = gtid >> 13;                       // dir*4 + b
    const int q   = gtid & (NPTS - 1);
    const int b   = group & 3;
    const int dir = group >> 2;
    const float* q_ptr = (dir == 0) ? xyz2 : xyz1;
    const float* d_ptr = (dir == 0) ? xyz1 : xyz2;

    const unsigned long long key = keys[gtid];
    const unsigned int smin_m = (unsigned int)(key >> 32);
    const int gbase = (int)(unsigned int)key;           // multiple of 8

    const float* qp = q_ptr + (size_t)(b * NPTS + q) * 3;
    const float qx = qp[0], qy = qp[1], qz = qp[2];

    // gather the 8 candidate db points (24 floats = 6 aligned float4)
    const float4* g4 = (const float4*)(d_ptr + (size_t)(b * NPTS + gbase) * 3);
    float4 t0 = g4[0], t1 = g4[1], t2 = g4[2], t3 = g4[3], t4 = g4[4], t5 = g4[5];
    float px[8] = {t0.x, t0.w, t1.z, t2.y, t3.x, t3.w, t4.z, t5.y};
    float py[8] = {t0.y, t1.x, t1.w, t2.z, t3.y, t4.x, t4.w, t5.z};
    float pz[8] = {t0.z, t1.y, t2.x, t2.w, t3.z, t4.y, t5.x, t5.w};

    int r = 0;
    float sx = px[0], sy = py[0], sz = pz[0];
#pragma unroll
    for (int k = 7; k >= 0; --k) {
        float ph = halfnorm(px[k], py[k], pz[k]);
        float s  = score(qx, qy, qz, px[k], py[k], pz[k], ph);
        if (mono_f32(s) == smin_m) { r = k; sx = px[k]; sy = py[k]; sz = pz[k]; }
    }
    const int idx = gbase + r;

    const float dx = qx - sx, dy = qy - sy, dz = qz - sz;
    const float d = dx * dx + dy * dy + dz * dz;
    const float e = expf(-1000.0f * d);

    atomicAdd(&counts[(size_t)group * NPTS + idx], 1u);
    atomicAdd(&esum[(size_t)group * NPTS + idx], e);
}

// ---------------------------------------------------------------------------
// Pass 3 (final): out = 1 - sum_p w(c_p) * e_p / 65536   (coalesced sweep)
//   dir0: w = 1 / max(1/c + 1e-6, 1)        (frac_21 = 1)
//   dir1: w = 1 / (c + 1e-6)                (ceil(frac_21) = 1)
// c==0 -> e==0 and w finite-or-zero -> contribution 0 (no NaN).
// ---------------------------------------------------------------------------
__global__ void __launch_bounds__(BLOCK) final_kernel(
        const unsigned int* __restrict__ counts,
        const float* __restrict__ esum,
        float* __restrict__ out) {
    __shared__ float red[4];
    const int gtid = blockIdx.x * BLOCK + threadIdx.x;  // 0..65535
    const int dir = gtid >> 15;                         // group = gtid>>13, dir = group>>2

    const float c = (float)counts[gtid];
    const float e = esum[gtid];
    float w;
    if (dir == 0) w = 1.0f / fmaxf(1.0f / c + 1e-6f, 1.0f);
    else          w = 1.0f / (c + 1e-6f);
    float term = -w * e;

#pragma unroll
    for (int off = 32; off > 0; off >>= 1)
        term += __shfl_down(term, off);
    const int lane = threadIdx.x & 63;
    const int wid  = threadIdx.x >> 6;
    if (lane == 0) red[wid] = term;
    __syncthreads();
    if (threadIdx.x == 0) {
        float t = red[0] + red[1] + red[2] + red[3];
        atomicAdd(out, t * (1.0f / 65536.0f));
    }
}

extern "C" void kernel_launch(void* const* d_in, const int* in_sizes, int n_in,
                              void* d_out, int out_size, void* d_ws, size_t ws_size,
                              hipStream_t stream) {
    const float* xyz1 = (const float*)d_in[0];  // prediction [4,8192,3]
    const float* xyz2 = (const float*)d_in[1];  // ground truth [4,8192,3]
    float* out = (float*)d_out;

    unsigned long long* keys = (unsigned long long*)d_ws;                     // 512 KB
    unsigned int* counts = (unsigned int*)((char*)d_ws + (size_t)NKEYS * 8);  // 256 KB
    float* esum = (float*)((char*)d_ws + (size_t)NKEYS * 12);                 // 256 KB

    hipMemsetAsync(keys, 0xFF, (size_t)NKEYS * 8, stream);

    nn_kernel<<<dim3(NPTS / QPB, NPTS / CHUNK, 2 * BATCH), BLOCK, 0, stream>>>(
        xyz1, xyz2, keys, counts, esum, out);
    mid_kernel<<<NKEYS / BLOCK, BLOCK, 0, stream>>>(xyz1, xyz2, keys, counts, esum);
    final_kernel<<<NKEYS / BLOCK, BLOCK, 0, stream>>>(counts, esum, out);
}

// Round 7
// 111.106 us; speedup vs baseline: 2.4834x; 2.4834x over previous
//
#include <hip/hip_runtime.h>
#include <cstdint>
#include <cstddef>

#define BATCH 4
#define NPTS 8192
#define CHUNK 128           // db points per block (NPTS / 64 chunks)
#define BLOCK 256           // threads per block
#define QPT 8               // queries per thread
#define QPB (BLOCK * QPT)   // 2048 queries per block
#define NKEYS (2 * BATCH * NPTS)  // 65536
// grid = (NPTS/QPB) x (NPTS/CHUNK) x (2*BATCH) = 4 x 64 x 8 = 2048 blocks
// = 8 blocks/CU target. launch_bounds(256,4): VGPR budget 128; r5 compiled
// this body to 64 VGPR -> HW allows 8 waves/SIMD; LDS 2KB/block is no cap.
// (r6's launch_bounds(256,8) forced 32 VGPR -> scratch spill -> 594MB HBM
// writes, 4x regression. Never tighten bounds below natural allocation.)

// ---------------------------------------------------------------------------
// Shared bit-exact helpers (used by nn staging, nn loop, and mid resolve —
// explicit fmaf chains so both kernels produce identical bits).
// ---------------------------------------------------------------------------
__device__ __forceinline__ float halfnorm(float px, float py, float pz) {
    return 0.5f * fmaf(pz, pz, fmaf(py, py, px * px));
}
__device__ __forceinline__ float score(float qx, float qy, float qz,
                                       float px, float py, float pz, float ph) {
    float t = fmaf(-qx, px, ph);
    t = fmaf(-qy, py, t);
    return fmaf(-qz, pz, t);
}
__device__ __forceinline__ unsigned int mono_f32(float f) {
    unsigned int u = __float_as_uint(f);
    return u ^ (unsigned int)(((int)u >> 31) | 0x80000000);
}

// ---------------------------------------------------------------------------
// Pass 1: brute-force NN.  s = 0.5*|p|^2 - q.p  (ordering == |q-p|^2).
// Group-of-8 min3 tree; only the winning GROUP BASE is tracked (strict <
// keeps earliest group). Cross-chunk combine: atomicMin on u64 key
//   (mono(s)<<32) | group_base  -> ties pick smallest base (first occurrence).
// Within-group index resolved later in mid_kernel (bit-identical recompute).
// Side duty (ct==0 blocks): zero counts/esum, out = 1.0.
// ---------------------------------------------------------------------------
__global__ void __launch_bounds__(BLOCK, 4) nn_kernel(
        const float* __restrict__ xyz1,
        const float* __restrict__ xyz2,
        unsigned long long* __restrict__ keys,
        unsigned int* __restrict__ counts,
        float* __restrict__ esum,
        float* __restrict__ out) {
    __shared__ float lx[CHUNK];
    __shared__ float ly[CHUNK];
    __shared__ float lz[CHUNK];
    __shared__ float lh[CHUNK];

    const int tid = threadIdx.x;
    const int qt  = blockIdx.x;      // 0..3   query tile (2048 queries)
    const int ct  = blockIdx.y;      // 0..63  db chunk (128 points)
    const int zb  = blockIdx.z;      // 0..7   dir*4 + b
    const int b   = zb & 3;
    const int dir = zb >> 2;
    const float* q_ptr = (dir == 0) ? xyz2 : xyz1;
    const float* d_ptr = (dir == 0) ? xyz1 : xyz2;
    const int chunk0 = ct * CHUNK;

    // ---- side duty (ct==0: 32 blocks x 256 threads = 8192 threads) ----
    if (ct == 0) {
        const int tz = (zb * 4 + qt) * BLOCK + tid;   // 0..8191
#pragma unroll
        for (int k = 0; k < 8; ++k) {
            counts[tz * 8 + k] = 0u;
            esum[tz * 8 + k] = 0.0f;
        }
        if (tz == 0) out[0] = 1.0f;
    }

    // ---- stage db chunk into LDS (SoA + half-norm) ----
    // CHUNK*3 = 384 floats = 96 float4; threads 0..31 load 3 float4 each
    if (tid < 32) {
        const float4* g4 = (const float4*)(d_ptr + (size_t)(b * NPTS + chunk0) * 3);
        float4 t0 = g4[3 * tid + 0];
        float4 t1 = g4[3 * tid + 1];
        float4 t2 = g4[3 * tid + 2];
        float px[4] = {t0.x, t0.w, t1.z, t2.y};
        float py[4] = {t0.y, t1.x, t1.w, t2.z};
        float pz[4] = {t0.z, t1.y, t2.x, t2.w};
#pragma unroll
        for (int i = 0; i < 4; ++i) {
            lx[4 * tid + i] = px[i];
            ly[4 * tid + i] = py[i];
            lz[4 * tid + i] = pz[i];
            lh[4 * tid + i] = halfnorm(px[i], py[i], pz[i]);
        }
    }

    // ---- this thread's QPT query points (stride BLOCK for coalescing) ----
    const int qbase = qt * QPB + tid;
    float qx[QPT], qy[QPT], qz[QPT];
#pragma unroll
    for (int u = 0; u < QPT; ++u) {
        const float* qp = q_ptr + (size_t)(b * NPTS + qbase + u * BLOCK) * 3;
        qx[u] = qp[0]; qy[u] = qp[1]; qz[u] = qp[2];
    }

    __syncthreads();

    float bd[QPT];
    int   bj[QPT];
#pragma unroll
    for (int u = 0; u < QPT; ++u) { bd[u] = 3.4e38f; bj[u] = 0; }

    for (int j = 0; j < CHUNK; j += 8) {
        float px[8], py[8], pz[8], ph[8];
        *(float4*)&px[0] = *(const float4*)(lx + j);
        *(float4*)&px[4] = *(const float4*)(lx + j + 4);
        *(float4*)&py[0] = *(const float4*)(ly + j);
        *(float4*)&py[4] = *(const float4*)(ly + j + 4);
        *(float4*)&pz[0] = *(const float4*)(lz + j);
        *(float4*)&pz[4] = *(const float4*)(lz + j + 4);
        *(float4*)&ph[0] = *(const float4*)(lh + j);
        *(float4*)&ph[4] = *(const float4*)(lh + j + 4);

#pragma unroll
        for (int u = 0; u < QPT; ++u) {
            float s[8];
#pragma unroll
            for (int k = 0; k < 8; ++k)
                s[k] = score(qx[u], qy[u], qz[u], px[k], py[k], pz[k], ph[k]);
            float m0 = fminf(fminf(s[0], s[1]), s[2]);   // v_min3
            float m1 = fminf(fminf(s[3], s[4]), s[5]);   // v_min3
            float m2 = fminf(fminf(s[6], s[7]), m0);     // v_min3
            float m  = fminf(m1, m2);
            if (m < bd[u]) { bd[u] = m; bj[u] = j; }     // strict <: earliest group
        }
    }

    const size_t base = ((size_t)zb) * NPTS;
#pragma unroll
    for (int u = 0; u < QPT; ++u) {
        unsigned long long key =
            ((unsigned long long)mono_f32(bd[u]) << 32) |
            (unsigned int)(chunk0 + bj[u]);
        atomicMin(&keys[base + qbase + u * BLOCK], key);
    }
}

// ---------------------------------------------------------------------------
// Pass 2 (mid): per query — resolve argmin within the winning group of 8 by
// bit-identical recompute from global memory, then accumulate histogram
// count and exp(-1000*d_exact) per chosen db point.
// ---------------------------------------------------------------------------
__global__ void __launch_bounds__(BLOCK) mid_kernel(
        const float* __restrict__ xyz1,
        const float* __restrict__ xyz2,
        const unsigned long long* __restrict__ keys,
        unsigned int* __restrict__ counts,
        float* __restrict__ esum) {
    const int gtid = blockIdx.x * BLOCK + threadIdx.x;  // 0..65535
    const int group = gtid >> 13;                       // dir*4 + b
    const int q   = gtid & (NPTS - 1);
    const int b   = group & 3;
    const int dir = group >> 2;
    const float* q_ptr = (dir == 0) ? xyz2 : xyz1;
    const float* d_ptr = (dir == 0) ? xyz1 : xyz2;

    const unsigned long long key = keys[gtid];
    const unsigned int smin_m = (unsigned int)(key >> 32);
    const int gbase = (int)(unsigned int)key;           // multiple of 8

    const float* qp = q_ptr + (size_t)(b * NPTS + q) * 3;
    const float qx = qp[0], qy = qp[1], qz = qp[2];

    // gather the 8 candidate db points (24 floats = 6 aligned float4)
    const float4* g4 = (const float4*)(d_ptr + (size_t)(b * NPTS + gbase) * 3);
    float4 t0 = g4[0], t1 = g4[1], t2 = g4[2], t3 = g4[3], t4 = g4[4], t5 = g4[5];
    float px[8] = {t0.x, t0.w, t1.z, t2.y, t3.x, t3.w, t4.z, t5.y};
    float py[8] = {t0.y, t1.x, t1.w, t2.z, t3.y, t4.x, t4.w, t5.z};
    float pz[8] = {t0.z, t1.y, t2.x, t2.w, t3.z, t4.y, t5.x, t5.w};

    int r = 0;
    float sx = px[0], sy = py[0], sz = pz[0];
#pragma unroll
    for (int k = 7; k >= 0; --k) {
        float ph = halfnorm(px[k], py[k], pz[k]);
        float s  = score(qx, qy, qz, px[k], py[k], pz[k], ph);
        if (mono_f32(s) == smin_m) { r = k; sx = px[k]; sy = py[k]; sz = pz[k]; }
    }
    const int idx = gbase + r;

    const float dx = qx - sx, dy = qy - sy, dz = qz - sz;
    const float d = dx * dx + dy * dy + dz * dz;
    const float e = expf(-1000.0f * d);

    atomicAdd(&counts[(size_t)group * NPTS + idx], 1u);
    atomicAdd(&esum[(size_t)group * NPTS + idx], e);
}

// ---------------------------------------------------------------------------
// Pass 3 (final): out = 1 - sum_p w(c_p) * e_p / 65536   (coalesced sweep)
//   dir0: w = 1 / max(1/c + 1e-6, 1)        (frac_21 = 1)
//   dir1: w = 1 / (c + 1e-6)                (ceil(frac_21) = 1)
// c==0 -> e==0 and w finite-or-zero -> contribution 0 (no NaN).
// ---------------------------------------------------------------------------
__global__ void __launch_bounds__(BLOCK) final_kernel(
        const unsigned int* __restrict__ counts,
        const float* __restrict__ esum,
        float* __restrict__ out) {
    __shared__ float red[4];
    const int gtid = blockIdx.x * BLOCK + threadIdx.x;  // 0..65535
    const int dir = gtid >> 15;                         // group = gtid>>13, dir = group>>2

    const float c = (float)counts[gtid];
    const float e = esum[gtid];
    float w;
    if (dir == 0) w = 1.0f / fmaxf(1.0f / c + 1e-6f, 1.0f);
    else          w = 1.0f / (c + 1e-6f);
    float term = -w * e;

#pragma unroll
    for (int off = 32; off > 0; off >>= 1)
        term += __shfl_down(term, off);
    const int lane = threadIdx.x & 63;
    const int wid  = threadIdx.x >> 6;
    if (lane == 0) red[wid] = term;
    __syncthreads();
    if (threadIdx.x == 0) {
        float t = red[0] + red[1] + red[2] + red[3];
        atomicAdd(out, t * (1.0f / 65536.0f));
    }
}

extern "C" void kernel_launch(void* const* d_in, const int* in_sizes, int n_in,
                              void* d_out, int out_size, void* d_ws, size_t ws_size,
                              hipStream_t stream) {
    const float* xyz1 = (const float*)d_in[0];  // prediction [4,8192,3]
    const float* xyz2 = (const float*)d_in[1];  // ground truth [4,8192,3]
    float* out = (float*)d_out;

    unsigned long long* keys = (unsigned long long*)d_ws;                     // 512 KB
    unsigned int* counts = (unsigned int*)((char*)d_ws + (size_t)NKEYS * 8);  // 256 KB
    float* esum = (float*)((char*)d_ws + (size_t)NKEYS * 12);                 // 256 KB

    hipMemsetAsync(keys, 0xFF, (size_t)NKEYS * 8, stream);

    nn_kernel<<<dim3(NPTS / QPB, NPTS / CHUNK, 2 * BATCH), BLOCK, 0, stream>>>(
        xyz1, xyz2, keys, counts, esum, out);
    mid_kernel<<<NKEYS / BLOCK, BLOCK, 0, stream>>>(xyz1, xyz2, keys, counts, esum);
    final_kernel<<<NKEYS / BLOCK, BLOCK, 0, stream>>>(counts, esum, out);
}